// Round 4
// baseline (890.057 us; speedup 1.0000x reference)
//
#include <hip/hip_runtime.h>

// FilteredPatchLoss: B=64, H=W=1024, p=16.
// Stripe = (b, ih): 16 rows x 1024 cols = 16384 floats, 64 patches per stripe.
// Thread t owns float4-column t (patch t/4) within each stripe.
//
// R6: revert R5's 3x probe (it measured T_main = (691-506)/2 = 92.2 us =
// 5.82 TB/s = 92.5% of the 6.29 TB/s achievable read ceiling -> main kernel
// is at the memory roofline; that's why R2/R3/R4 were time-identical).
// Window: ~324 us unconditional ws-poison fills + ~92 us main + ~5 us reduce
// + ~85 us harness restore dispatches. Only remaining controllable item:
// the separate reduce dispatch. Fused here via threadfence+ticket last-block
// reduction (device-scope atomics; ticket self-resets for graph replay).
// Main loop body byte-identical to the verified 92-us R4 version.

#define PATCH 16
#define WIDTH 1024
#define SPB 2  // stripes per block

// 4096 stripes * 4 waves = 16384 per-(stripe,wave) partials (128 KB .bss)
#define MAX_PARTIALS 16384

__device__ float2 g_partials[MAX_PARTIALS];
__device__ unsigned int g_ticket;  // .bss zero-init; last block resets it

__global__ __launch_bounds__(256, 4) void patch_loss_kernel(
    const float* __restrict__ outp, const float* __restrict__ tgtp,
    const int* __restrict__ filter_rate_p, float* __restrict__ out)
{
    const int t = threadIdx.x;
    const float fr = (float)(*filter_rate_p);

#pragma unroll
    for (int s = 0; s < SPB; ++s) {
        const int stripe = blockIdx.x * SPB + s;
        const long long base = (long long)stripe * (PATCH * WIDTH);
        const float4* op = (const float4*)(outp + base) + t;
        const float4* tp = (const float4*)(tgtp + base) + t;

        float ts = 0.f, ls = 0.f;
#pragma unroll
        for (int kc = 0; kc < 16; kc += 4) {
            float4 o0 = op[(kc + 0) * 256];
            float4 g0 = tp[(kc + 0) * 256];
            float4 o1 = op[(kc + 1) * 256];
            float4 g1 = tp[(kc + 1) * 256];
            float4 o2 = op[(kc + 2) * 256];
            float4 g2 = tp[(kc + 2) * 256];
            float4 o3 = op[(kc + 3) * 256];
            float4 g3 = tp[(kc + 3) * 256];

            ts += (g0.x + g0.y) + (g0.z + g0.w);
            ls += (fabsf(o0.x - g0.x) + fabsf(o0.y - g0.y)) +
                  (fabsf(o0.z - g0.z) + fabsf(o0.w - g0.w));
            ts += (g1.x + g1.y) + (g1.z + g1.w);
            ls += (fabsf(o1.x - g1.x) + fabsf(o1.y - g1.y)) +
                  (fabsf(o1.z - g1.z) + fabsf(o1.w - g1.w));
            ts += (g2.x + g2.y) + (g2.z + g2.w);
            ls += (fabsf(o2.x - g2.x) + fabsf(o2.y - g2.y)) +
                  (fabsf(o2.z - g2.z) + fabsf(o2.w - g2.w));
            ts += (g3.x + g3.y) + (g3.z + g3.w);
            ls += (fabsf(o3.x - g3.x) + fabsf(o3.y - g3.y)) +
                  (fabsf(o3.z - g3.z) + fabsf(o3.w - g3.w));
        }

        // Patch p <- lanes 4p..4p+3 (contiguous, same wave).
        ts += __shfl_xor(ts, 1, 64);
        ls += __shfl_xor(ls, 1, 64);
        ts += __shfl_xor(ts, 2, 64);
        ls += __shfl_xor(ls, 2, 64);

        const bool live = ((t & 3) == 0) && (ts * (1.0f / 256.0f) > fr);
        float loss = live ? ls * (1.0f / 256.0f) : 0.0f;
        float cnt  = live ? 1.0f : 0.0f;

#pragma unroll
        for (int off = 4; off <= 32; off <<= 1) {
            loss += __shfl_xor(loss, off, 64);
            cnt  += __shfl_xor(cnt,  off, 64);
        }
        if ((t & 63) == 0)
            g_partials[(stripe << 2) | (t >> 6)] = make_float2(loss, cnt);
    }

    // ---- fused final reduction: last-arriving block finishes the job ----
    __threadfence();   // each writer's partial store -> device-visible
    __syncthreads();   // all 4 waves' stores+fences precede the ticket
    __shared__ unsigned int s_rank;
    if (t == 0) s_rank = atomicAdd(&g_ticket, 1u);
    __syncthreads();
    if (s_rank == (unsigned)(gridDim.x - 1)) {  // block-uniform condition
        __threadfence();  // acquire side: see all blocks' partials
        const float4* p = (const float4*)g_partials;
        float l = 0.f, c = 0.f;
        for (int i = t; i < MAX_PARTIALS / 2; i += 256) {
            float4 v = p[i];
            l += v.x + v.z;
            c += v.y + v.w;
        }
#pragma unroll
        for (int off = 1; off <= 32; off <<= 1) {
            l += __shfl_xor(l, off, 64);
            c += __shfl_xor(c, off, 64);
        }
        __shared__ float sl[4], sc[4];
        if ((t & 63) == 0) { sl[t >> 6] = l; sc[t >> 6] = c; }
        __syncthreads();
        if (t == 0) {
            l = (sl[0] + sl[1]) + (sl[2] + sl[3]);
            c = (sc[0] + sc[1]) + (sc[2] + sc[3]);
            out[0] = l / c;
            g_ticket = 0;  // reset for next graph replay
        }
    }
}

extern "C" void kernel_launch(void* const* d_in, const int* in_sizes, int n_in,
                              void* d_out, int out_size, void* d_ws, size_t ws_size,
                              hipStream_t stream)
{
    const float* outp = (const float*)d_in[0];
    const float* tgtp = (const float*)d_in[1];
    // d_in[2] = patch_size (16, structure hard-coded), d_in[3] = filter_rate
    const int* filter_rate_p = (const int*)d_in[3];

    const long long total = (long long)in_sizes[0];          // B*H*W
    const int nstripes = (int)(total / (PATCH * WIDTH));     // 4096
    const int nblocks = nstripes / SPB;                      // 2048

    patch_loss_kernel<<<nblocks, 256, 0, stream>>>(
        outp, tgtp, filter_rate_p, (float*)d_out);
}

// Round 5
// 507.064 us; speedup vs baseline: 1.7553x; 1.7553x over previous
//
#include <hip/hip_runtime.h>

// FilteredPatchLoss: B=64, H=W=1024, p=16.
// Stripe = (b, ih): 16 rows x 1024 cols = 16384 floats, 64 patches per stripe.
// Thread t owns float4-column t (patch t/4) within each stripe.
//
// R7: REVERT to the verified R4 two-kernel structure. R6's fused last-block
// reduction was a 6x main-kernel regression (92 -> 552 us, hbm 487 GB/s,
// VGPR 36): the agent-scope __threadfence per block lowers to per-XCD L2
// writeback/invalidate (2048 invalidation events thrash the stream), and the
// fused epilogue pushed regalloc to 36 VGPRs, serializing the chunk loads.
// Measured facts driving the final state:
//   - T_main = 92.2 us (R5 3x-launch probe) = 5.82 TB/s = 92.5% of the
//     6.29 TB/s achievable read ceiling (m13). R2/R3/R4 (three different
//     schedules) time-identical -> memory roofline.
//   - Timed window = ~324 us unconditional 2x1GiB ws-poison fills
//     + ~85 us harness restore dispatches + 92 us main + ~5 us reduce.
//     Only the last two are kernel-addressable; they are at the floor.

#define PATCH 16
#define WIDTH 1024
#define SPB 2  // stripes per block

// 4096 stripes * 4 waves = 16384 per-(stripe,wave) partials (128 KB .bss)
#define MAX_PARTIALS 16384

__device__ float2 g_partials[MAX_PARTIALS];

__global__ __launch_bounds__(256, 4) void patch_loss_kernel(
    const float* __restrict__ outp, const float* __restrict__ tgtp,
    const int* __restrict__ filter_rate_p)
{
    const int t = threadIdx.x;
    const float fr = (float)(*filter_rate_p);

#pragma unroll
    for (int s = 0; s < SPB; ++s) {
        const int stripe = blockIdx.x * SPB + s;
        const long long base = (long long)stripe * (PATCH * WIDTH);
        const float4* op = (const float4*)(outp + base) + t;
        const float4* tp = (const float4*)(tgtp + base) + t;

        float ts = 0.f, ls = 0.f;
#pragma unroll
        for (int kc = 0; kc < 16; kc += 4) {
            float4 o0 = op[(kc + 0) * 256];
            float4 g0 = tp[(kc + 0) * 256];
            float4 o1 = op[(kc + 1) * 256];
            float4 g1 = tp[(kc + 1) * 256];
            float4 o2 = op[(kc + 2) * 256];
            float4 g2 = tp[(kc + 2) * 256];
            float4 o3 = op[(kc + 3) * 256];
            float4 g3 = tp[(kc + 3) * 256];

            ts += (g0.x + g0.y) + (g0.z + g0.w);
            ls += (fabsf(o0.x - g0.x) + fabsf(o0.y - g0.y)) +
                  (fabsf(o0.z - g0.z) + fabsf(o0.w - g0.w));
            ts += (g1.x + g1.y) + (g1.z + g1.w);
            ls += (fabsf(o1.x - g1.x) + fabsf(o1.y - g1.y)) +
                  (fabsf(o1.z - g1.z) + fabsf(o1.w - g1.w));
            ts += (g2.x + g2.y) + (g2.z + g2.w);
            ls += (fabsf(o2.x - g2.x) + fabsf(o2.y - g2.y)) +
                  (fabsf(o2.z - g2.z) + fabsf(o2.w - g2.w));
            ts += (g3.x + g3.y) + (g3.z + g3.w);
            ls += (fabsf(o3.x - g3.x) + fabsf(o3.y - g3.y)) +
                  (fabsf(o3.z - g3.z) + fabsf(o3.w - g3.w));
        }

        // Patch p <- lanes 4p..4p+3 (contiguous, same wave).
        ts += __shfl_xor(ts, 1, 64);
        ls += __shfl_xor(ls, 1, 64);
        ts += __shfl_xor(ts, 2, 64);
        ls += __shfl_xor(ls, 2, 64);

        const bool live = ((t & 3) == 0) && (ts * (1.0f / 256.0f) > fr);
        float loss = live ? ls * (1.0f / 256.0f) : 0.0f;
        float cnt  = live ? 1.0f : 0.0f;

#pragma unroll
        for (int off = 4; off <= 32; off <<= 1) {
            loss += __shfl_xor(loss, off, 64);
            cnt  += __shfl_xor(cnt,  off, 64);
        }
        if ((t & 63) == 0)
            g_partials[(stripe << 2) | (t >> 6)] = make_float2(loss, cnt);
    }
}

// Single block: reduce 16384 (loss, cnt) pairs and finalize.
__global__ __launch_bounds__(1024) void reduce_kernel(
    float* __restrict__ out, int nf4)  // nf4 = nwaves/2 float4 views
{
    const int t = threadIdx.x;
    const float4* p = (const float4*)g_partials;
    float l = 0.f, c = 0.f;
    for (int i = t; i < nf4; i += 1024) {
        float4 v = p[i];
        l += v.x + v.z;
        c += v.y + v.w;
    }
#pragma unroll
    for (int off = 1; off <= 32; off <<= 1) {
        l += __shfl_xor(l, off, 64);
        c += __shfl_xor(c, off, 64);
    }
    __shared__ float sl[16], sc[16];
    if ((t & 63) == 0) { sl[t >> 6] = l; sc[t >> 6] = c; }
    __syncthreads();
    if (t < 64) {  // one full wave active -> shuffles well-defined
        l = (t < 16) ? sl[t] : 0.f;
        c = (t < 16) ? sc[t] : 0.f;
#pragma unroll
        for (int off = 1; off <= 8; off <<= 1) {
            l += __shfl_xor(l, off, 64);
            c += __shfl_xor(c, off, 64);
        }
        if (t == 0) out[0] = l / c;
    }
}

extern "C" void kernel_launch(void* const* d_in, const int* in_sizes, int n_in,
                              void* d_out, int out_size, void* d_ws, size_t ws_size,
                              hipStream_t stream)
{
    const float* outp = (const float*)d_in[0];
    const float* tgtp = (const float*)d_in[1];
    // d_in[2] = patch_size (16, structure hard-coded), d_in[3] = filter_rate
    const int* filter_rate_p = (const int*)d_in[3];

    const long long total = (long long)in_sizes[0];          // B*H*W
    const int nstripes = (int)(total / (PATCH * WIDTH));     // 4096
    const int nblocks = nstripes / SPB;                      // 2048
    const int nf4 = nstripes * 2;                            // nwaves/2 = 8192

    patch_loss_kernel<<<nblocks, 256, 0, stream>>>(outp, tgtp, filter_rate_p);
    reduce_kernel<<<1, 1024, 0, stream>>>((float*)d_out, nf4);
}